// Round 1
// baseline (451.484 us; speedup 1.0000x reference)
//
#include <hip/hip_runtime.h>
#include <math.h>

// ResidualGATLayer on MI355X.
// Inputs (setup_inputs order): x[f32 N*128], edge_index[int 2*E], W[f32 128*128],
// a_src[f32 4*32], a_dst[f32 4*32], bias[f32 128]. Output f32 N*128.

#define CH 128   // IN_CH == HEADS*OUT_CH

// ---------------- Kernel 1: h = x @ W (f32) + alpha_s/alpha_d ----------------
// Block 256 threads = 2 groups of 128 (one thread per output channel).
// W staged in 64KB LDS; each group computes 4 nodes at a time; 64 nodes/block.
__global__ __launch_bounds__(256) void gemm_alpha(
    const float* __restrict__ x, const float* __restrict__ W,
    const float* __restrict__ a_src, const float* __restrict__ a_dst,
    float* __restrict__ h, float* __restrict__ as_, float* __restrict__ ad_, int N)
{
    __shared__ float Wl[CH * CH];           // 64 KiB
    for (int i = threadIdx.x * 4; i < CH * CH; i += 256 * 4) {
        *(float4*)&Wl[i] = *(const float4*)&W[i];
    }
    const int c = threadIdx.x & 127;        // output channel
    const int g = threadIdx.x >> 7;         // node sub-group 0/1
    // a_src is [4][32] contiguous -> flat index == channel index
    const float asr = a_src[c];
    const float adr = a_dst[c];
    __syncthreads();

    const int base = blockIdx.x * 64;
    for (int nb = base + g * 4; nb < base + 64; nb += 8) {
        if (nb >= N) break;                 // N % 4 == 0, nb % 4 == 0
        float acc0 = 0.f, acc1 = 0.f, acc2 = 0.f, acc3 = 0.f;
        const float* x0 = &x[(size_t)nb * CH];
        #pragma unroll 8
        for (int k4 = 0; k4 < CH; k4 += 4) {
            float4 xv0 = *(const float4*)&x0[k4];
            float4 xv1 = *(const float4*)&x0[CH + k4];
            float4 xv2 = *(const float4*)&x0[2 * CH + k4];
            float4 xv3 = *(const float4*)&x0[3 * CH + k4];
            float xa0[4] = {xv0.x, xv0.y, xv0.z, xv0.w};
            float xa1[4] = {xv1.x, xv1.y, xv1.z, xv1.w};
            float xa2[4] = {xv2.x, xv2.y, xv2.z, xv2.w};
            float xa3[4] = {xv3.x, xv3.y, xv3.z, xv3.w};
            #pragma unroll
            for (int kk = 0; kk < 4; ++kk) {
                float w = Wl[(k4 + kk) * CH + c];
                acc0 += xa0[kk] * w;
                acc1 += xa1[kk] * w;
                acc2 += xa2[kk] * w;
                acc3 += xa3[kk] * w;
            }
        }
        float accs[4] = {acc0, acc1, acc2, acc3};
        #pragma unroll
        for (int j = 0; j < 4; ++j) {
            float s = accs[j] * asr;
            float d = accs[j] * adr;
            #pragma unroll
            for (int m = 1; m < 32; m <<= 1) {      // reduce within 32-lane head group
                s += __shfl_xor(s, m, 64);
                d += __shfl_xor(d, m, 64);
            }
            h[(size_t)(nb + j) * CH + c] = accs[j];
            if ((c & 31) == 0) {
                as_[(nb + j) * 4 + (c >> 5)] = s;
                ad_[(nb + j) * 4 + (c >> 5)] = d;
            }
        }
    }
}

// ---------------- CSR build ----------------
__global__ void init_deg(int* __restrict__ deg, int* __restrict__ cursor, int N) {
    int i = blockIdx.x * blockDim.x + threadIdx.x;
    if (i < N) { deg[i] = 1; cursor[i] = 0; }   // 1 = self loop
}

__global__ void hist(const int* __restrict__ dst, int* __restrict__ deg, int E) {
    int i = blockIdx.x * blockDim.x + threadIdx.x;
    if (i < E) atomicAdd(&deg[dst[i]], 1);
}

// Single-block exclusive scan of deg[0..N) -> row_start[0..N]
__global__ __launch_bounds__(1024) void scan_deg(const int* __restrict__ deg,
                                                 int* __restrict__ row_start, int N)
{
    __shared__ int wsum[16];
    __shared__ int carry_s;
    if (threadIdx.x == 0) { carry_s = 0; row_start[0] = 0; }
    __syncthreads();
    const int lane = threadIdx.x & 63;
    const int w = threadIdx.x >> 6;
    for (int base = 0; base < N; base += 1024) {
        int i = base + (int)threadIdx.x;
        int v = (i < N) ? deg[i] : 0;
        int s = v;
        #pragma unroll
        for (int off = 1; off < 64; off <<= 1) {
            int t = __shfl_up(s, off, 64);
            if (lane >= off) s += t;
        }
        if (lane == 63) wsum[w] = s;
        __syncthreads();
        if (threadIdx.x < 16) {
            int t = wsum[threadIdx.x];
            #pragma unroll
            for (int off = 1; off < 16; off <<= 1) {
                int u = __shfl_up(t, off, 64);
                if ((int)threadIdx.x >= off) t += u;
            }
            wsum[threadIdx.x] = t;
        }
        __syncthreads();
        int carry = carry_s;
        int incl = s + ((w > 0) ? wsum[w - 1] : 0) + carry;
        if (i < N) row_start[i + 1] = incl;
        __syncthreads();
        if (threadIdx.x == 1023) carry_s = incl;   // = carry + tile total
        __syncthreads();
    }
}

__global__ void scatter_edges(const int* __restrict__ src, const int* __restrict__ dst,
                              const int* __restrict__ row_start, int* __restrict__ cursor,
                              int* __restrict__ esrc, int E, int N)
{
    int i = blockIdx.x * blockDim.x + threadIdx.x;
    int total = E + N;
    if (i >= total) return;
    int s, d;
    if (i < E) { s = src[i]; d = dst[i]; }
    else       { s = i - E;  d = s; }              // self loops
    int pos = row_start[d] + atomicAdd(&cursor[d], 1);
    esrc[pos] = s;
}

// ---------------- Kernel 5: per-node softmax-weighted aggregation ----------------
// One wave per destination node. Lane owns channels {lane, lane+64}.
// Softmax without max-subtraction (shift-invariant; logits are O(few)).
__global__ __launch_bounds__(256) void gat_aggregate(
    const float* __restrict__ h, const float* __restrict__ as_, const float* __restrict__ ad_,
    const int* __restrict__ row_start, const int* __restrict__ esrc,
    const float* __restrict__ bias, const float* __restrict__ x,
    float* __restrict__ out, int N)
{
    int wid = (int)((blockIdx.x * (size_t)blockDim.x + threadIdx.x) >> 6);
    int lane = (int)(threadIdx.x & 63);
    if (wid >= N) return;
    const int n = wid;
    const int hsel = lane >> 5;                    // 0/1: head {0|1} for c0, {2|3} for c1

    float4 adn = *(const float4*)&ad_[n * 4];
    const float ad0 = hsel ? adn.y : adn.x;
    const float ad1 = hsel ? adn.w : adn.z;

    float den0 = 0.f, den1 = 0.f, acc0 = 0.f, acc1 = 0.f;
    const int jb = row_start[n], je = row_start[n + 1];
    for (int j = jb; j < je; ++j) {
        int s = esrc[j];
        float4 a4 = *(const float4*)&as_[s * 4];
        float e0 = (hsel ? a4.y : a4.x) + ad0;
        float e1 = (hsel ? a4.w : a4.z) + ad1;
        e0 = (e0 < 0.f) ? 0.2f * e0 : e0;          // LeakyReLU(0.2)
        e1 = (e1 < 0.f) ? 0.2f * e1 : e1;
        float p0 = expf(e0);
        float p1 = expf(e1);
        den0 += p0; den1 += p1;
        const float* hr = &h[(size_t)s * CH];
        acc0 += p0 * hr[lane];
        acc1 += p1 * hr[64 + lane];
    }
    float o0 = acc0 / (den0 + 1e-16f) + bias[lane];
    float o1 = acc1 / (den1 + 1e-16f) + bias[64 + lane];
    o0 = (o0 > 0.f) ? o0 : expm1f(o0);             // ELU
    o1 = (o1 > 0.f) ? o1 : expm1f(o1);
    out[(size_t)n * CH + lane]      = o0 + x[(size_t)n * CH + lane];
    out[(size_t)n * CH + 64 + lane] = o1 + x[(size_t)n * CH + 64 + lane];
}

extern "C" void kernel_launch(void* const* d_in, const int* in_sizes, int n_in,
                              void* d_out, int out_size, void* d_ws, size_t ws_size,
                              hipStream_t stream) {
    const float* x     = (const float*)d_in[0];
    const int*   ei    = (const int*)d_in[1];
    const float* W     = (const float*)d_in[2];
    const float* a_src = (const float*)d_in[3];
    const float* a_dst = (const float*)d_in[4];
    const float* bias  = (const float*)d_in[5];
    float* out = (float*)d_out;

    const int N = in_sizes[0] / CH;       // 50000
    const int E = in_sizes[1] / 2;        // 800000
    const int* src = ei;
    const int* dst = ei + E;

    // workspace layout
    float* h   = (float*)d_ws;
    float* as_ = h + (size_t)N * CH;
    float* ad_ = as_ + (size_t)N * 4;
    int* deg       = (int*)(ad_ + (size_t)N * 4);
    int* cursor    = deg + N;
    int* row_start = cursor + N;
    int* esrc      = row_start + (N + 1);

    gemm_alpha<<<(N + 63) / 64, 256, 0, stream>>>(x, W, a_src, a_dst, h, as_, ad_, N);
    init_deg<<<(N + 255) / 256, 256, 0, stream>>>(deg, cursor, N);
    hist<<<(E + 255) / 256, 256, 0, stream>>>(dst, deg, E);
    scan_deg<<<1, 1024, 0, stream>>>(deg, row_start, N);
    scatter_edges<<<(E + N + 255) / 256, 256, 0, stream>>>(src, dst, row_start, cursor, esrc, E, N);
    gat_aggregate<<<(N + 3) / 4, 256, 0, stream>>>(h, as_, ad_, row_start, esrc, bias, x, out, N);
}

// Round 2
// 292.442 us; speedup vs baseline: 1.5438x; 1.5438x over previous
//
#include <hip/hip_runtime.h>
#include <math.h>

// ResidualGATLayer on MI355X.
// Inputs: x[f32 N*128], edge_index[int 2*E], W[f32 128*128],
// a_src[f32 4*32], a_dst[f32 4*32], bias[f32 128]. Output f32 N*128.

#define CH 128

typedef short bf16x8 __attribute__((ext_vector_type(8)));
typedef float f32x4 __attribute__((ext_vector_type(4)));

__device__ __forceinline__ short f2bf(float f) {
    unsigned int u = __builtin_bit_cast(unsigned int, f);
    u += 0x7FFFu + ((u >> 16) & 1u);          // RNE
    return (short)(u >> 16);
}

// ---------------- Kernel 1: h = x @ W via bf16 MFMA ----------------
// Block 256 = 4 waves; 64 nodes/block; wave w -> rows [w*16, w*16+16), all 128 cols.
// W staged transposed (Wt[n][k]) bf16 in LDS with XOR swizzle on 16B granularity.
__global__ __launch_bounds__(256) void gemm_mfma(
    const float* __restrict__ x, const float* __restrict__ W,
    float* __restrict__ h, int N)
{
    __shared__ short Wl[CH * CH];             // 32 KiB, swizzled [n][k']
    for (int i = threadIdx.x; i < CH * CH; i += 256) {
        int k = i >> 7, n = i & 127;
        int kp = ((((k >> 3) ^ (n & 7)) << 3) | (k & 7));
        Wl[n * CH + kp] = f2bf(W[i]);
    }
    __syncthreads();

    const int w = threadIdx.x >> 6, l = threadIdx.x & 63;
    const int m0 = blockIdx.x * 64 + w * 16;
    const int lr = l & 15, lg = l >> 4;
    int arow = m0 + lr; if (arow >= N) arow = N - 1;       // clamp (stores guarded)

    // A-fragments: row = l&15, k = lg*8 + j  (4 K-steps of 32)
    bf16x8 afr[4];
    const float* xr = &x[(size_t)arow * CH + lg * 8];
    #pragma unroll
    for (int ks = 0; ks < 4; ++ks) {
        float4 p0 = *(const float4*)&xr[ks * 32];
        float4 p1 = *(const float4*)&xr[ks * 32 + 4];
        afr[ks][0] = f2bf(p0.x); afr[ks][1] = f2bf(p0.y);
        afr[ks][2] = f2bf(p0.z); afr[ks][3] = f2bf(p0.w);
        afr[ks][4] = f2bf(p1.x); afr[ks][5] = f2bf(p1.y);
        afr[ks][6] = f2bf(p1.z); afr[ks][7] = f2bf(p1.w);
    }

    f32x4 acc[8];
    #pragma unroll
    for (int nt = 0; nt < 8; ++nt) acc[nt] = (f32x4){0.f, 0.f, 0.f, 0.f};

    #pragma unroll
    for (int ks = 0; ks < 4; ++ks) {
        #pragma unroll
        for (int nt = 0; nt < 8; ++nt) {
            int col = nt * 16 + lr;
            int kb8 = ks * 4 + lg;
            bf16x8 bfr = *(const bf16x8*)&Wl[col * CH + ((kb8 ^ (col & 7)) << 3)];
            acc[nt] = __builtin_amdgcn_mfma_f32_16x16x32_bf16(afr[ks], bfr, acc[nt], 0, 0, 0);
        }
    }

    // C/D: col = l&15, row = lg*4 + reg
    #pragma unroll
    for (int nt = 0; nt < 8; ++nt) {
        #pragma unroll
        for (int r = 0; r < 4; ++r) {
            int orow = m0 + lg * 4 + r;
            if (orow < N) h[(size_t)orow * CH + nt * 16 + lr] = acc[nt][r];
        }
    }
}

// ---------------- Kernel 2: alpha_s/alpha_d from h ----------------
__global__ __launch_bounds__(256) void alpha_kernel(
    const float* __restrict__ h, const float* __restrict__ a_src,
    const float* __restrict__ a_dst, float* __restrict__ as_,
    float* __restrict__ ad_, int N)
{
    int wid = blockIdx.x * 4 + (threadIdx.x >> 6);
    int lane = threadIdx.x & 63;
    if (wid >= N) return;
    float h0 = h[(size_t)wid * CH + lane];
    float h1 = h[(size_t)wid * CH + 64 + lane];
    float s0 = h0 * a_src[lane], s1 = h1 * a_src[64 + lane];
    float d0 = h0 * a_dst[lane], d1 = h1 * a_dst[64 + lane];
    #pragma unroll
    for (int m = 1; m < 32; m <<= 1) {
        s0 += __shfl_xor(s0, m, 64); s1 += __shfl_xor(s1, m, 64);
        d0 += __shfl_xor(d0, m, 64); d1 += __shfl_xor(d1, m, 64);
    }
    if ((lane & 31) == 0) {
        int hh = lane >> 5;
        as_[wid * 4 + hh] = s0;  as_[wid * 4 + 2 + hh] = s1;
        ad_[wid * 4 + hh] = d0;  ad_[wid * 4 + 2 + hh] = d1;
    }
}

// ---------------- CSR build ----------------
__global__ void init_deg(int* __restrict__ deg, int* __restrict__ cursor, int N) {
    int i = blockIdx.x * blockDim.x + threadIdx.x;
    if (i < N) { deg[i] = 1; cursor[i] = 0; }   // 1 = self loop
}

__global__ void hist(const int* __restrict__ dst, int* __restrict__ deg, int E) {
    int i = blockIdx.x * blockDim.x + threadIdx.x;
    if (i < E) atomicAdd(&deg[dst[i]], 1);
}

// Single-block exclusive scan (int4-vectorized, 4096 elems/iteration)
__global__ __launch_bounds__(1024) void scan_deg(const int* __restrict__ deg,
                                                 int* __restrict__ row_start, int N)
{
    __shared__ int wsum[16];
    __shared__ int carry_s;
    if (threadIdx.x == 0) { carry_s = 0; row_start[0] = 0; }
    __syncthreads();
    const int lane = threadIdx.x & 63;
    const int w = threadIdx.x >> 6;
    const int nv = (N + 3) >> 2;
    for (int base = 0; base < nv; base += 1024) {
        int i4 = base + (int)threadIdx.x;
        int4 v = make_int4(0, 0, 0, 0);
        int e0 = i4 * 4;
        if (e0 + 3 < N)      v = *(const int4*)&deg[e0];
        else if (e0 < N) {
            v.x = deg[e0];
            if (e0 + 1 < N) v.y = deg[e0 + 1];
            if (e0 + 2 < N) v.z = deg[e0 + 2];
        }
        int t = v.x + v.y + v.z + v.w;
        int s = t;
        #pragma unroll
        for (int off = 1; off < 64; off <<= 1) {
            int u = __shfl_up(s, off, 64);
            if (lane >= off) s += u;
        }
        if (lane == 63) wsum[w] = s;
        __syncthreads();
        if (threadIdx.x < 16) {
            int tt = wsum[threadIdx.x];
            #pragma unroll
            for (int off = 1; off < 16; off <<= 1) {
                int u = __shfl_up(tt, off, 64);
                if ((int)threadIdx.x >= off) tt += u;
            }
            wsum[threadIdx.x] = tt;
        }
        __syncthreads();
        int excl = s - t + ((w > 0) ? wsum[w - 1] : 0) + carry_s;
        int p = excl;
        if (e0 < N)     { row_start[e0 + 1] = p + v.x; p += v.x; }
        if (e0 + 1 < N) { row_start[e0 + 2] = p + v.y; p += v.y; }
        if (e0 + 2 < N) { row_start[e0 + 3] = p + v.z; p += v.z; }
        if (e0 + 3 < N) { row_start[e0 + 4] = p + v.w; }
        __syncthreads();
        if (threadIdx.x == 1023) carry_s = excl + t;
        __syncthreads();
    }
}

__global__ void scatter_edges(const int* __restrict__ src, const int* __restrict__ dst,
                              const int* __restrict__ row_start, int* __restrict__ cursor,
                              int* __restrict__ esrc, int E, int N)
{
    int i = blockIdx.x * blockDim.x + threadIdx.x;
    int total = E + N;
    if (i >= total) return;
    int s, d;
    if (i < E) { s = src[i]; d = dst[i]; }
    else       { s = i - E;  d = s; }              // self loops
    int pos = row_start[d] + atomicAdd(&cursor[d], 1);
    esrc[pos] = s;
}

// ---------------- Kernel 5: per-node softmax-weighted aggregation ----------------
// One wave per destination node. Lane owns channels {2*lane, 2*lane+1} -> one head/lane.
__global__ __launch_bounds__(256) void gat_aggregate(
    const float* __restrict__ h, const float* __restrict__ as_, const float* __restrict__ ad_,
    const int* __restrict__ row_start, const int* __restrict__ esrc,
    const float* __restrict__ bias, const float* __restrict__ x,
    float* __restrict__ out, int N)
{
    int wid = blockIdx.x * 4 + (threadIdx.x >> 6);
    int lane = threadIdx.x & 63;
    if (wid >= N) return;
    const int head = lane >> 4;                    // channel 2*lane -> head (2*lane)>>5
    const float adv = ad_[wid * 4 + head];

    float den = 0.f, acc0 = 0.f, acc1 = 0.f;
    const int jb = row_start[wid], je = row_start[wid + 1];
    int j = jb;
    for (; j + 1 < je; j += 2) {
        int s0 = esrc[j], s1 = esrc[j + 1];
        float e0 = as_[s0 * 4 + head] + adv;
        float e1 = as_[s1 * 4 + head] + adv;
        float2 h0 = *(const float2*)&h[(size_t)s0 * CH + 2 * lane];
        float2 h1 = *(const float2*)&h[(size_t)s1 * CH + 2 * lane];
        e0 = (e0 < 0.f) ? 0.2f * e0 : e0;
        e1 = (e1 < 0.f) ? 0.2f * e1 : e1;
        float p0 = __expf(e0), p1 = __expf(e1);
        den += p0 + p1;
        acc0 = fmaf(p0, h0.x, fmaf(p1, h1.x, acc0));
        acc1 = fmaf(p0, h0.y, fmaf(p1, h1.y, acc1));
    }
    if (j < je) {
        int s0 = esrc[j];
        float e0 = as_[s0 * 4 + head] + adv;
        float2 h0 = *(const float2*)&h[(size_t)s0 * CH + 2 * lane];
        e0 = (e0 < 0.f) ? 0.2f * e0 : e0;
        float p0 = __expf(e0);
        den += p0;
        acc0 = fmaf(p0, h0.x, acc0);
        acc1 = fmaf(p0, h0.y, acc1);
    }
    float inv = 1.f / (den + 1e-16f);
    float o0 = acc0 * inv + bias[2 * lane];
    float o1 = acc1 * inv + bias[2 * lane + 1];
    o0 = (o0 > 0.f) ? o0 : expm1f(o0);             // ELU
    o1 = (o1 > 0.f) ? o1 : expm1f(o1);
    float2 xv = *(const float2*)&x[(size_t)wid * CH + 2 * lane];
    float2 ov; ov.x = o0 + xv.x; ov.y = o1 + xv.y;
    *(float2*)&out[(size_t)wid * CH + 2 * lane] = ov;
}

extern "C" void kernel_launch(void* const* d_in, const int* in_sizes, int n_in,
                              void* d_out, int out_size, void* d_ws, size_t ws_size,
                              hipStream_t stream) {
    const float* x     = (const float*)d_in[0];
    const int*   ei    = (const int*)d_in[1];
    const float* W     = (const float*)d_in[2];
    const float* a_src = (const float*)d_in[3];
    const float* a_dst = (const float*)d_in[4];
    const float* bias  = (const float*)d_in[5];
    float* out = (float*)d_out;

    const int N = in_sizes[0] / CH;       // 50000
    const int E = in_sizes[1] / 2;        // 800000
    const int* src = ei;
    const int* dst = ei + E;

    float* h   = (float*)d_ws;
    float* as_ = h + (size_t)N * CH;
    float* ad_ = as_ + (size_t)N * 4;
    int* deg       = (int*)(ad_ + (size_t)N * 4);
    int* cursor    = deg + N;
    int* row_start = cursor + N;
    int* esrc      = row_start + (N + 1);

    gemm_mfma<<<(N + 63) / 64, 256, 0, stream>>>(x, W, h, N);
    init_deg<<<(N + 255) / 256, 256, 0, stream>>>(deg, cursor, N);
    hist<<<(E + 255) / 256, 256, 0, stream>>>(dst, deg, E);
    scan_deg<<<1, 1024, 0, stream>>>(deg, row_start, N);
    scatter_edges<<<(E + N + 255) / 256, 256, 0, stream>>>(src, dst, row_start, cursor, esrc, E, N);
    alpha_kernel<<<(N + 3) / 4, 256, 0, stream>>>(h, a_src, a_dst, as_, ad_, N);
    gat_aggregate<<<(N + 3) / 4, 256, 0, stream>>>(h, as_, ad_, row_start, esrc, bias, x, out, N);
}